// Round 18
// baseline (136.981 us; speedup 1.0000x reference)
//
#include <hip/hip_runtime.h>
#include <math.h>

// EdgeDegreeEmbeddingNetwork — algebraically reduced, scatter-free, CSR-ordered.
// fp32 everywhere. R18 = R17 minus the Tbuf round-trip:
//   t_build is FUSED into proj as a per-branch phase-0. Each branch only needs
//   its own k-slice of T (l0: k=0, l1: k=1..3, l2: k=4..8), so each block
//   builds that slice directly from h2csr/ya_csr into the LDS tiles proj
//   already uses, overlapped with M staging, then runs the proven block-GEMM.
//   h2csr is read 3x (61 MB) but Tbuf (23+23 MB), ysb, and one kernel launch
//   disappear. edge_h2 / precompute / scan: byte-identical to R17 (proven).

#define NEDGES 80000
#define NNODES 10000
#define NB_L0  157     // ceil(10000/64)
#define NB_L12 313     // ceil(10000/32)

__device__ __forceinline__ float silu_f(float y) {
    return y / (1.0f + __expf(-y));
}

// ---- Fused: precompute M (64x224), c (224)  +  dst histogram ----------------
__global__ __launch_bounds__(256) void precompute_and_hist(
    const float* __restrict__ exp_w, const float* __restrict__ exp_b,
    const float* __restrict__ rad_w3,     // 64 x 960
    const float* __restrict__ rad_offset, // 960
    const float* __restrict__ proj_w0,    // 224 x 128 (rows 0..127 live)
    const float* __restrict__ proj_w1,    // 384 x 64
    const float* __restrict__ proj_w2,    // 352 x 32
    float* __restrict__ M, float* __restrict__ cvec,
    const int* __restrict__ edge_dst, int* __restrict__ counts)
{
    if (blockIdx.x >= 65) {
        int b = blockIdx.x - 65;
        for (int e = b * 256 + threadIdx.x; e < NEDGES; e += 100 * 256)
            atomicAdd(&counts[edge_dst[e]], 1);
        return;
    }
    __shared__ float x0[128];
    int t = threadIdx.x;
    if (t < 128) x0[t] = exp_w[t] + exp_b[t];
    __syncthreads();
    if (t >= 224) return;
    int h = blockIdx.x; // 0..63 -> M rows, 64 -> c
    const float* src = (h < 64) ? (rad_w3 + h * 960) : rad_offset;
    float acc = 0.0f;
    if (t < 128) {
#pragma unroll 4
        for (int u = 0; u < 128; ++u) acc += src[u] * x0[u] * proj_w0[u * 128 + t];
    } else if (t < 192) {
        int o = t - 128;
#pragma unroll 4
        for (int u = 0; u < 128; ++u) acc += src[128 + u] * x0[u] * proj_w1[u * 64 + o];
    } else {
        int o = t - 192;
#pragma unroll 4
        for (int u = 0; u < 128; ++u) acc += src[256 + u] * x0[u] * proj_w2[u * 32 + o];
    }
    if (h < 64) M[h * 224 + t] = acc;
    else        cvec[t] = acc;
}

// ---- CSR: exclusive scan of counts via wave shuffles -------------------------
__global__ __launch_bounds__(1024) void scan_counts(
    int* __restrict__ counts, int* __restrict__ offsets)
{
    __shared__ int wsum[16];
    const int t = threadIdx.x;
    const int lane = t & 63, w = t >> 6;
    const int base = t * 10;
    int local[10];
    int s = 0;
#pragma unroll
    for (int i = 0; i < 10; ++i) {
        int idx = base + i;
        int v = (idx < NNODES) ? counts[idx] : 0;
        local[i] = s;
        s += v;
    }
    int incl = s;
#pragma unroll
    for (int off = 1; off < 64; off <<= 1) {
        int up = __shfl_up(incl, off, 64);
        if (lane >= off) incl += up;
    }
    if (lane == 63) wsum[w] = incl;
    __syncthreads();
    if (t < 16) {
        int v = wsum[t];
#pragma unroll
        for (int off = 1; off < 16; off <<= 1) {
            int up = __shfl_up(v, off, 64);
            if (t >= off) v += up;
        }
        wsum[t] = v;
    }
    __syncthreads();
    int wbase = (w == 0) ? 0 : wsum[w - 1];
    int excl = wbase + incl - s;
#pragma unroll
    for (int i = 0; i < 10; ++i) {
        int idx = base + i;
        if (idx < NNODES) {
            offsets[idx] = excl + local[i];
            counts[idx] = 0;
        }
    }
    if (t == 1023) offsets[NNODES] = excl + s;
}

// ---- Phase A: 4x4 register-tiled LDS GEMM MLP (W1 in LDS, W2 via L1) --------
__global__ __launch_bounds__(256) void edge_h2(
    const float* __restrict__ edge_scalars, // E x 128
    const float* __restrict__ edge_attr,    // E x 9
    const int*   __restrict__ edge_dst,
    const int*   __restrict__ offsets,
    int*         __restrict__ cursor,
    const float* __restrict__ rad_w1,       // 128 x 64 [k][n]
    const float* __restrict__ rad_b1,
    const float* __restrict__ g1, const float* __restrict__ bt1,
    const float* __restrict__ rad_w2,       // 64 x 64 [u][n] (L1-hot, 16KB)
    const float* __restrict__ rad_b2,
    const float* __restrict__ g2, const float* __restrict__ bt2,
    float* __restrict__ h2csr,              // E x 64 (CSR row order)
    float* __restrict__ ya_csr)             // E x 9  (CSR row order)
{
    __shared__ float S[12288 + 64];
    float* W1s = S;              // [128][64] 32 KB; later: per-wave h1^T [64][20]
    float* ES  = S + 8192;       // [64][64] 16 KB: es_t k-half (swizzled), h2 buf
    int*   pos_s = (int*)(S + 12288);

    const int t    = threadIdx.x;
    const int lane = t & 63;
    const int wid  = t >> 6;
    const int er   = lane & 3;   // edge sub-tile
    const int cc   = lane >> 2;  // channel sub-tile
    const int eb   = blockIdx.x * 64;

    // ---- stage W1 (8 f4/thr), linear, coalesced ----------------------------
    {
        const float4* s1 = (const float4*)rad_w1;
        float4* d1 = (float4*)W1s;
#pragma unroll
        for (int i = 0; i < 8; ++i) d1[t + i * 256] = s1[t + i * 256];
    }
    // ---- CSR positions + ya gather for this block's 64 edges ---------------
    if (t < 64) {
        int e = eb + t;
        int d = edge_dst[e];
        int p = offsets[d] + atomicAdd(&cursor[d], 1);
        pos_s[t] = p;
        const float* ya = edge_attr + (size_t)e * 9;
        float* dst = ya_csr + (size_t)p * 9;
#pragma unroll
        for (int k = 0; k < 9; ++k) dst[k] = ya[k];
    }
    // ---- stage es_t half0 (k=0..63), swizzled col = e ^ (seg<<3) -----------
    {
        const int re = t >> 2, seg = t & 3;
        const int col = re ^ (seg << 3);    // seg = k>>4
        const float* row = edge_scalars + (size_t)(eb + re) * 128;
#pragma unroll
        for (int q = 0; q < 4; ++q) {
            float4 v = *(const float4*)(row + seg * 16 + q * 4);
            ES[(seg * 16 + q * 4 + 0) * 64 + col] = v.x;
            ES[(seg * 16 + q * 4 + 1) * 64 + col] = v.y;
            ES[(seg * 16 + q * 4 + 2) * 64 + col] = v.z;
            ES[(seg * 16 + q * 4 + 3) * 64 + col] = v.w;
        }
    }
    __syncthreads();

    // per-lane channel params (n = cc*4+j)
    const int n0 = cc * 4;
    float b1v[4], g1v[4], t1v[4], b2v[4], g2v[4], t2v[4];
#pragma unroll
    for (int j = 0; j < 4; ++j) {
        b1v[j] = rad_b1[n0 + j]; g1v[j] = g1[n0 + j]; t1v[j] = bt1[n0 + j];
        b2v[j] = rad_b2[n0 + j]; g2v[j] = g2[n0 + j]; t2v[j] = bt2[n0 + j];
    }

    float acc[4][4];
#pragma unroll
    for (int i = 0; i < 4; ++i)
#pragma unroll
        for (int j = 0; j < 4; ++j) acc[i][j] = b1v[j];

    const int ecol = wid * 16 + er * 4;

    // ---- GEMM1 half0: k = 0..63 (read un-swizzles: col = ecol ^ ((k>>4)<<3))
#pragma unroll 8
    for (int k = 0; k < 64; ++k) {
        float4 av = *(const float4*)&ES[k * 64 + (ecol ^ (((k >> 4) & 3) << 3))];
        float4 wv = *(const float4*)&W1s[k * 64 + n0];    // 2-way (free)
        float a4[4] = {av.x, av.y, av.z, av.w};
        float w4[4] = {wv.x, wv.y, wv.z, wv.w};
#pragma unroll
        for (int i = 0; i < 4; ++i)
#pragma unroll
            for (int j = 0; j < 4; ++j) acc[i][j] = fmaf(a4[i], w4[j], acc[i][j]);
    }
    __syncthreads();
    // ---- stage es_t half1 (k=64..127), same swizzle ------------------------
    {
        const int re = t >> 2, seg = t & 3;
        const int col = re ^ (seg << 3);
        const float* row = edge_scalars + (size_t)(eb + re) * 128 + 64;
#pragma unroll
        for (int q = 0; q < 4; ++q) {
            float4 v = *(const float4*)(row + seg * 16 + q * 4);
            ES[(seg * 16 + q * 4 + 0) * 64 + col] = v.x;
            ES[(seg * 16 + q * 4 + 1) * 64 + col] = v.y;
            ES[(seg * 16 + q * 4 + 2) * 64 + col] = v.z;
            ES[(seg * 16 + q * 4 + 3) * 64 + col] = v.w;
        }
    }
    __syncthreads();
    // ---- GEMM1 half1: k = 64..127 ------------------------------------------
#pragma unroll 8
    for (int k = 0; k < 64; ++k) {
        float4 av = *(const float4*)&ES[k * 64 + (ecol ^ (((k >> 4) & 3) << 3))];
        float4 wv = *(const float4*)&W1s[(64 + k) * 64 + n0];
        float a4[4] = {av.x, av.y, av.z, av.w};
        float w4[4] = {wv.x, wv.y, wv.z, wv.w};
#pragma unroll
        for (int i = 0; i < 4; ++i)
#pragma unroll
            for (int j = 0; j < 4; ++j) acc[i][j] = fmaf(a4[i], w4[j], acc[i][j]);
    }
    __syncthreads();  // all W1s/ES reads complete; regions reusable

    // ---- LN1 + silu -> h1^T tile in (old W1s) per-wave region [64][20] -----
    float* H = W1s + wid * 1280;
    {
        float s1i[4], s2i[4];
#pragma unroll
        for (int i = 0; i < 4; ++i) {
            s1i[i] = acc[i][0] + acc[i][1] + acc[i][2] + acc[i][3];
            s2i[i] = acc[i][0] * acc[i][0] + acc[i][1] * acc[i][1]
                   + acc[i][2] * acc[i][2] + acc[i][3] * acc[i][3];
        }
#pragma unroll
        for (int m = 4; m <= 32; m <<= 1) {
#pragma unroll
            for (int i = 0; i < 4; ++i) {
                s1i[i] += __shfl_xor(s1i[i], m, 64);
                s2i[i] += __shfl_xor(s2i[i], m, 64);
            }
        }
#pragma unroll
        for (int i = 0; i < 4; ++i) {
            float mu  = s1i[i] * (1.0f / 64.0f);
            float var = s2i[i] * (1.0f / 64.0f) - mu * mu;
            float rs  = rsqrtf(var + 1e-5f);
#pragma unroll
            for (int j = 0; j < 4; ++j) {
                float y = (acc[i][j] - mu) * rs * g1v[j] + t1v[j];
                H[(n0 + j) * 20 + er * 4 + i] = silu_f(y);
            }
        }
    }

    // ---- GEMM2: c = h1 @ W2 (h1 from LDS, W2 from global/L1) ---------------
    float acc2[4][4];
#pragma unroll
    for (int i = 0; i < 4; ++i)
#pragma unroll
        for (int j = 0; j < 4; ++j) acc2[i][j] = b2v[j];
#pragma unroll 8
    for (int u = 0; u < 64; ++u) {
        float4 hv = *(const float4*)&H[u * 20 + er * 4];   // DS, conflict-free
        float4 wv = *(const float4*)&rad_w2[u * 64 + n0];  // VMEM (L1, 16KB)
        float h4[4] = {hv.x, hv.y, hv.z, hv.w};
        float w4[4] = {wv.x, wv.y, wv.z, wv.w};
#pragma unroll
        for (int i = 0; i < 4; ++i)
#pragma unroll
            for (int j = 0; j < 4; ++j) acc2[i][j] = fmaf(h4[i], w4[j], acc2[i][j]);
    }

    // ---- LN2 + silu -> h2 rows assembled in (old ES) buffer ----------------
    {
        float s1i[4], s2i[4];
#pragma unroll
        for (int i = 0; i < 4; ++i) {
            s1i[i] = acc2[i][0] + acc2[i][1] + acc2[i][2] + acc2[i][3];
            s2i[i] = acc2[i][0] * acc2[i][0] + acc2[i][1] * acc2[i][1]
                   + acc2[i][2] * acc2[i][2] + acc2[i][3] * acc2[i][3];
        }
#pragma unroll
        for (int m = 4; m <= 32; m <<= 1) {
#pragma unroll
            for (int i = 0; i < 4; ++i) {
                s1i[i] += __shfl_xor(s1i[i], m, 64);
                s2i[i] += __shfl_xor(s2i[i], m, 64);
            }
        }
#pragma unroll
        for (int i = 0; i < 4; ++i) {
            float mu  = s1i[i] * (1.0f / 64.0f);
            float var = s2i[i] * (1.0f / 64.0f) - mu * mu;
            float rs  = rsqrtf(var + 1e-5f);
            float4 v;
            v.x = silu_f((acc2[i][0] - mu) * rs * g2v[0] + t2v[0]);
            v.y = silu_f((acc2[i][1] - mu) * rs * g2v[1] + t2v[1]);
            v.z = silu_f((acc2[i][2] - mu) * rs * g2v[2] + t2v[2]);
            v.w = silu_f((acc2[i][3] - mu) * rs * g2v[3] + t2v[3]);
            *(float4*)&ES[(wid * 16 + er * 4 + i) * 64 + n0] = v;
        }
    }
    __syncthreads();

    // ---- epilogue: coalesced float4 writes at CSR positions ----------------
    {
        const int r = t >> 2, p = t & 3;
        int pos = pos_s[r];
        float* dst = h2csr + (size_t)pos * 64 + p * 16;
        const float* src = &ES[r * 64 + p * 16];
#pragma unroll
        for (int q = 0; q < 4; ++q)
            *(float4*)(dst + q * 4) = *(const float4*)(src + q * 4);
    }
}

// ---- Phase B (fused): per-branch T-slice build + block GEMM -----------------
__global__ __launch_bounds__(256) void proj_fused(
    const float* __restrict__ h2csr,  // E x 64 (CSR order)
    const float* __restrict__ ya_csr, // E x 9  (CSR order)
    const int*   __restrict__ offsets,
    const float* __restrict__ M,      // 64 x 224
    const float* __restrict__ cvec,   // 224
    const float* __restrict__ proj_b, // 128
    float* __restrict__ out)          // NNODES x 480
{
    __shared__ float S[13248];
    const int tid  = threadIdx.x;
    const int bid  = blockIdx.x;
    const int lane = tid & 63;
    const int wid  = tid >> 6;
    constexpr float inv = 0.35355339059327373f;

    if (bid < NB_L0) {
        // ============== l0: k=0, 64 nodes, cols 0..127 =======================
        const int n0 = bid * 64;
        float* ys0_s = S + 12416; // [64]
        // M0 -> [u][128] @4224 (overlaps phase-0 below, both done at barrier)
        for (int it = tid; it < 2048; it += 256) {
            int u = it >> 5, c4 = it & 31;
            *(float4*)&S[4224 + u * 128 + c4 * 4] = *(const float4*)&M[u * 224 + c4 * 4];
        }
        // phase-0: build T0 tile [u][66] directly; wave handles 16 nodes
        for (int nn = 0; nn < 16; ++nn) {
            int ni = (wid << 4) | nn;
            int n  = n0 + ni;
            int s0 = 0, s1 = 0;
            if (n < NNODES) { s0 = offsets[n]; s1 = offsets[n + 1]; }
            float T0 = 0.0f, ys0 = 0.0f;
            for (int i = s0; i < s1; ++i) {
                float hv = h2csr[(size_t)i * 64 + lane];
                float y0 = ya_csr[(size_t)i * 9];
                T0 = fmaf(hv, y0, T0);
                ys0 += y0;
            }
            S[lane * 66 + ni] = T0;
            if (lane == 0) ys0_s[ni] = ys0;
        }
        __syncthreads();
        const int np = tid & 15, cg = tid >> 4;
        float acc[4][8];
#pragma unroll
        for (int i = 0; i < 4; ++i)
#pragma unroll
            for (int j = 0; j < 8; ++j) acc[i][j] = 0.0f;
#pragma unroll 4
        for (int u = 0; u < 64; ++u) {
            float4 tv = *(const float4*)&S[u * 66 + np * 4];
            float4 m0 = *(const float4*)&S[4224 + u * 128 + cg * 8];
            float4 m1 = *(const float4*)&S[4224 + u * 128 + cg * 8 + 4];
            float ta[4] = {tv.x, tv.y, tv.z, tv.w};
            float ma[8] = {m0.x, m0.y, m0.z, m0.w, m1.x, m1.y, m1.z, m1.w};
#pragma unroll
            for (int i = 0; i < 4; ++i)
#pragma unroll
                for (int j = 0; j < 8; ++j) acc[i][j] = fmaf(ta[i], ma[j], acc[i][j]);
        }
#pragma unroll
        for (int i = 0; i < 4; ++i) {
            int ni = np * 4 + i;
            int n = n0 + ni;
            if (n >= NNODES) continue;
            float ys0 = ys0_s[ni];
            float cnt = (float)(offsets[n + 1] - offsets[n]);
            float f[8];
#pragma unroll
            for (int j = 0; j < 8; ++j) {
                int col = cg * 8 + j;
                f[j] = (acc[i][j] + cvec[col] * ys0 + cnt * proj_b[col]) * inv;
            }
            *(float4*)&out[(size_t)n * 480 + cg * 8]     = *(float4*)&f[0];
            *(float4*)&out[(size_t)n * 480 + cg * 8 + 4] = *(float4*)&f[4];
        }
    } else if (bid < NB_L0 + NB_L12) {
        // ============== l1: k=1..3, 32 nodes, cols 128..319 ==================
        const int n0 = (bid - NB_L0) * 32;
        float* ysl = S + 10624; // [32][3]
        for (int it = tid; it < 1024; it += 256) {      // M1 -> [u][64] @6528
            int u = it >> 4, c4 = it & 15;
            *(float4*)&S[6528 + u * 64 + c4 * 4] = *(const float4*)&M[u * 224 + 128 + c4 * 4];
        }
        // phase-0: build T1..3 tiles [kq][u][34]; wave handles 8 nodes
        for (int nn = 0; nn < 8; ++nn) {
            int ni = (wid << 3) | nn;
            int n  = n0 + ni;
            int s0 = 0, s1 = 0;
            if (n < NNODES) { s0 = offsets[n]; s1 = offsets[n + 1]; }
            float T1 = 0.0f, T2 = 0.0f, T3 = 0.0f;
            float y1s = 0.0f, y2s = 0.0f, y3s = 0.0f;
            for (int i = s0; i < s1; ++i) {
                float hv = h2csr[(size_t)i * 64 + lane];
                const float* ya = ya_csr + (size_t)i * 9;
                float y1 = ya[1], y2 = ya[2], y3 = ya[3];
                T1 = fmaf(hv, y1, T1);
                T2 = fmaf(hv, y2, T2);
                T3 = fmaf(hv, y3, T3);
                y1s += y1; y2s += y2; y3s += y3;
            }
            S[0 * 2176 + lane * 34 + ni] = T1;
            S[1 * 2176 + lane * 34 + ni] = T2;
            S[2 * 2176 + lane * 34 + ni] = T3;
            if (lane == 0) {
                ysl[ni * 3 + 0] = y1s;
                ysl[ni * 3 + 1] = y2s;
                ysl[ni * 3 + 2] = y3s;
            }
        }
        __syncthreads();
        const int np = tid & 15, cg = tid >> 4;
        float acc[2][4][3];
#pragma unroll
        for (int i = 0; i < 2; ++i)
#pragma unroll
            for (int j = 0; j < 4; ++j)
#pragma unroll
                for (int kq = 0; kq < 3; ++kq) acc[i][j][kq] = 0.0f;
#pragma unroll 4
        for (int u = 0; u < 64; ++u) {
            float2 t0 = *(const float2*)&S[0 * 2176 + u * 34 + np * 2];
            float2 t1 = *(const float2*)&S[1 * 2176 + u * 34 + np * 2];
            float2 t2 = *(const float2*)&S[2 * 2176 + u * 34 + np * 2];
            float4 m  = *(const float4*)&S[6528 + u * 64 + cg * 4];
            float ma[4] = {m.x, m.y, m.z, m.w};
            float ta[2][3] = {{t0.x, t1.x, t2.x}, {t0.y, t1.y, t2.y}};
#pragma unroll
            for (int i = 0; i < 2; ++i)
#pragma unroll
                for (int j = 0; j < 4; ++j) {
                    acc[i][j][0] = fmaf(ta[i][0], ma[j], acc[i][j][0]);
                    acc[i][j][1] = fmaf(ta[i][1], ma[j], acc[i][j][1]);
                    acc[i][j][2] = fmaf(ta[i][2], ma[j], acc[i][j][2]);
                }
        }
#pragma unroll
        for (int i = 0; i < 2; ++i) {
            int ni = np * 2 + i;
            int n = n0 + ni;
            if (n >= NNODES) continue;
            float y1 = ysl[ni * 3 + 0], y2 = ysl[ni * 3 + 1], y3 = ysl[ni * 3 + 2];
            float f[12];
#pragma unroll
            for (int j = 0; j < 4; ++j) {
                int cc = cg * 4 + j;
                float cv = cvec[128 + cc];
                f[j * 3 + 0] = (acc[i][j][0] + cv * y1) * inv;
                f[j * 3 + 1] = (acc[i][j][1] + cv * y2) * inv;
                f[j * 3 + 2] = (acc[i][j][2] + cv * y3) * inv;
            }
            float* dst = &out[(size_t)n * 480 + 128 + cg * 12];
            *(float4*)(dst + 0) = *(float4*)&f[0];
            *(float4*)(dst + 4) = *(float4*)&f[4];
            *(float4*)(dst + 8) = *(float4*)&f[8];
        }
    } else {
        // ============== l2: k=4..8, 32 nodes, cols 320..479 ==================
        const int n0 = (bid - NB_L0 - NB_L12) * 32;
        float* ysl = S + 12928; // [32][5]
        for (int it = tid; it < 512; it += 256) {       // M2 -> [u][32] @10880
            int u = it >> 3, c4 = it & 7;
            *(float4*)&S[10880 + u * 32 + c4 * 4] = *(const float4*)&M[u * 224 + 192 + c4 * 4];
        }
        // phase-0: build T4..8 tiles [kq][u][34]; wave handles 8 nodes
        for (int nn = 0; nn < 8; ++nn) {
            int ni = (wid << 3) | nn;
            int n  = n0 + ni;
            int s0 = 0, s1 = 0;
            if (n < NNODES) { s0 = offsets[n]; s1 = offsets[n + 1]; }
            float T[5] = {0, 0, 0, 0, 0};
            float ys[5] = {0, 0, 0, 0, 0};
            for (int i = s0; i < s1; ++i) {
                float hv = h2csr[(size_t)i * 64 + lane];
                const float* ya = ya_csr + (size_t)i * 9;
#pragma unroll
                for (int kq = 0; kq < 5; ++kq) {
                    float y = ya[4 + kq];
                    T[kq] = fmaf(hv, y, T[kq]);
                    ys[kq] += y;
                }
            }
#pragma unroll
            for (int kq = 0; kq < 5; ++kq)
                S[kq * 2176 + lane * 34 + ni] = T[kq];
            if (lane == 0) {
#pragma unroll
                for (int kq = 0; kq < 5; ++kq) ysl[ni * 5 + kq] = ys[kq];
            }
        }
        __syncthreads();
        const int np = tid & 15, cg = tid >> 4;
        float acc[2][2][5];
#pragma unroll
        for (int i = 0; i < 2; ++i)
#pragma unroll
            for (int j = 0; j < 2; ++j)
#pragma unroll
                for (int kq = 0; kq < 5; ++kq) acc[i][j][kq] = 0.0f;
#pragma unroll 4
        for (int u = 0; u < 64; ++u) {
            float2 tq[5];
#pragma unroll
            for (int kq = 0; kq < 5; ++kq)
                tq[kq] = *(const float2*)&S[kq * 2176 + u * 34 + np * 2];
            float2 m = *(const float2*)&S[10880 + u * 32 + cg * 2];
            float ma[2] = {m.x, m.y};
#pragma unroll
            for (int i = 0; i < 2; ++i) {
                float ti[5] = {(&tq[0].x)[i], (&tq[1].x)[i], (&tq[2].x)[i],
                               (&tq[3].x)[i], (&tq[4].x)[i]};
#pragma unroll
                for (int j = 0; j < 2; ++j)
#pragma unroll
                    for (int kq = 0; kq < 5; ++kq)
                        acc[i][j][kq] = fmaf(ti[kq], ma[j], acc[i][j][kq]);
            }
        }
#pragma unroll
        for (int i = 0; i < 2; ++i) {
            int ni = np * 2 + i;
            int n = n0 + ni;
            if (n >= NNODES) continue;
            float yk[5];
#pragma unroll
            for (int kq = 0; kq < 5; ++kq) yk[kq] = ysl[ni * 5 + kq];
            float f[10];
#pragma unroll
            for (int j = 0; j < 2; ++j) {
                int cc = cg * 2 + j;
                float cv = cvec[192 + cc];
#pragma unroll
                for (int kq = 0; kq < 5; ++kq)
                    f[j * 5 + kq] = (acc[i][j][kq] + cv * yk[kq]) * inv;
            }
            float* dst = &out[(size_t)n * 480 + 320 + cg * 10];
#pragma unroll
            for (int q = 0; q < 5; ++q)
                *(float2*)(dst + q * 2) = *(float2*)&f[q * 2];
        }
    }
}

extern "C" void kernel_launch(void* const* d_in, const int* in_sizes, int n_in,
                              void* d_out, int out_size, void* d_ws, size_t ws_size,
                              hipStream_t stream)
{
    const float* edge_attr    = (const float*)d_in[1];
    const float* edge_scalars = (const float*)d_in[2];
    const int*   edge_dst     = (const int*)d_in[4];
    const float* exp_w   = (const float*)d_in[6];
    const float* exp_b   = (const float*)d_in[7];
    const float* rad_w1  = (const float*)d_in[8];
    const float* rad_b1  = (const float*)d_in[9];
    const float* g1      = (const float*)d_in[10];
    const float* bt1     = (const float*)d_in[11];
    const float* rad_w2  = (const float*)d_in[12];
    const float* rad_b2  = (const float*)d_in[13];
    const float* g2      = (const float*)d_in[14];
    const float* bt2     = (const float*)d_in[15];
    const float* rad_w3  = (const float*)d_in[16];
    const float* rad_off = (const float*)d_in[17];
    const float* pw0     = (const float*)d_in[18];
    const float* pw1     = (const float*)d_in[19];
    const float* pw2     = (const float*)d_in[20];
    const float* proj_b  = (const float*)d_in[21];

    // Workspace (~24 MB)
    float* M       = (float*)d_ws;                        // 14336 f
    float* cvec    = M + 14336;                           // 224 f
    float* h2csr   = cvec + 224;                          // 5,120,000 f
    int*   counts  = (int*)(h2csr + (size_t)NEDGES * 64); // 10000
    int*   offsets = counts + NNODES;                     // 10001
    float* ya_csr  = (float*)(offsets + NNODES + 1);      // 720,000 f

    hipMemsetAsync(counts, 0, NNODES * sizeof(int), stream);
    precompute_and_hist<<<165, 256, 0, stream>>>(exp_w, exp_b, rad_w3, rad_off,
        pw0, pw1, pw2, M, cvec, edge_dst, counts);
    scan_counts<<<1, 1024, 0, stream>>>(counts, offsets);
    edge_h2<<<NEDGES / 64, 256, 0, stream>>>(edge_scalars, edge_attr, edge_dst,
        offsets, counts, rad_w1, rad_b1, g1, bt1, rad_w2, rad_b2, g2, bt2,
        h2csr, ya_csr);
    proj_fused<<<NB_L0 + 2 * NB_L12, 256, 0, stream>>>(h2csr, ya_csr, offsets,
        M, cvec, proj_b, (float*)d_out);
}

// Round 19
// 122.796 us; speedup vs baseline: 1.1155x; 1.1155x over previous
//
#include <hip/hip_runtime.h>
#include <math.h>

// EdgeDegreeEmbeddingNetwork — algebraically reduced, scatter-free, CSR-ordered.
// fp32 everywhere. R19 = R17 (proven best, 109us) + shfl-GEMM2 in edge_h2:
//   h1 never leaves registers. After LN1, acc[i][j] = h1[e][u=cc*4+j]; GEMM2's
//   operand h1[e][u=4a+b] is fetched by __shfl(acc[i][b], a*4+er) — deletes
//   64 ds_read_b128 + 16 h1-stores + the H LDS tile per wave (~20% of the
//   measured DS-pipe budget; DS is the bound, VALU has headroom).
// R18 lesson (fusion regression): latency-bound phases need parallelism, not
// fusion — t_build stays a separate 10000-wave kernel.
// t_build / proj / precompute / scan: byte-identical to R17 (proven).

#define NEDGES 80000
#define NNODES 10000
#define NPAD   10048   // T buffer rows (157*64)
#define NB_L0  157     // ceil(10000/64)
#define NB_L12 313     // ceil(10000/32)

__device__ __forceinline__ float silu_f(float y) {
    return y / (1.0f + __expf(-y));
}

// ---- Fused: precompute M (64x224), c (224)  +  dst histogram ----------------
__global__ __launch_bounds__(256) void precompute_and_hist(
    const float* __restrict__ exp_w, const float* __restrict__ exp_b,
    const float* __restrict__ rad_w3,     // 64 x 960
    const float* __restrict__ rad_offset, // 960
    const float* __restrict__ proj_w0,    // 224 x 128 (rows 0..127 live)
    const float* __restrict__ proj_w1,    // 384 x 64
    const float* __restrict__ proj_w2,    // 352 x 32
    float* __restrict__ M, float* __restrict__ cvec,
    const int* __restrict__ edge_dst, int* __restrict__ counts)
{
    if (blockIdx.x >= 65) {
        int b = blockIdx.x - 65;
        for (int e = b * 256 + threadIdx.x; e < NEDGES; e += 100 * 256)
            atomicAdd(&counts[edge_dst[e]], 1);
        return;
    }
    __shared__ float x0[128];
    int t = threadIdx.x;
    if (t < 128) x0[t] = exp_w[t] + exp_b[t];
    __syncthreads();
    if (t >= 224) return;
    int h = blockIdx.x; // 0..63 -> M rows, 64 -> c
    const float* src = (h < 64) ? (rad_w3 + h * 960) : rad_offset;
    float acc = 0.0f;
    if (t < 128) {
#pragma unroll 4
        for (int u = 0; u < 128; ++u) acc += src[u] * x0[u] * proj_w0[u * 128 + t];
    } else if (t < 192) {
        int o = t - 128;
#pragma unroll 4
        for (int u = 0; u < 128; ++u) acc += src[128 + u] * x0[u] * proj_w1[u * 64 + o];
    } else {
        int o = t - 192;
#pragma unroll 4
        for (int u = 0; u < 128; ++u) acc += src[256 + u] * x0[u] * proj_w2[u * 32 + o];
    }
    if (h < 64) M[h * 224 + t] = acc;
    else        cvec[t] = acc;
}

// ---- CSR: exclusive scan of counts via wave shuffles -------------------------
__global__ __launch_bounds__(1024) void scan_counts(
    int* __restrict__ counts, int* __restrict__ offsets)
{
    __shared__ int wsum[16];
    const int t = threadIdx.x;
    const int lane = t & 63, w = t >> 6;
    const int base = t * 10;
    int local[10];
    int s = 0;
#pragma unroll
    for (int i = 0; i < 10; ++i) {
        int idx = base + i;
        int v = (idx < NNODES) ? counts[idx] : 0;
        local[i] = s;
        s += v;
    }
    int incl = s;
#pragma unroll
    for (int off = 1; off < 64; off <<= 1) {
        int up = __shfl_up(incl, off, 64);
        if (lane >= off) incl += up;
    }
    if (lane == 63) wsum[w] = incl;
    __syncthreads();
    if (t < 16) {
        int v = wsum[t];
#pragma unroll
        for (int off = 1; off < 16; off <<= 1) {
            int up = __shfl_up(v, off, 64);
            if (t >= off) v += up;
        }
        wsum[t] = v;
    }
    __syncthreads();
    int wbase = (w == 0) ? 0 : wsum[w - 1];
    int excl = wbase + incl - s;
#pragma unroll
    for (int i = 0; i < 10; ++i) {
        int idx = base + i;
        if (idx < NNODES) {
            offsets[idx] = excl + local[i];
            counts[idx] = 0;
        }
    }
    if (t == 1023) offsets[NNODES] = excl + s;
}

// ---- Phase A: 4x4 register-tiled LDS GEMM MLP, shfl-GEMM2 -------------------
__global__ __launch_bounds__(256) void edge_h2(
    const float* __restrict__ edge_scalars, // E x 128
    const float* __restrict__ edge_attr,    // E x 9
    const int*   __restrict__ edge_dst,
    const int*   __restrict__ offsets,
    int*         __restrict__ cursor,
    const float* __restrict__ rad_w1,       // 128 x 64 [k][n]
    const float* __restrict__ rad_b1,
    const float* __restrict__ g1, const float* __restrict__ bt1,
    const float* __restrict__ rad_w2,       // 64 x 64 [u][n] (L1-hot, 16KB)
    const float* __restrict__ rad_b2,
    const float* __restrict__ g2, const float* __restrict__ bt2,
    float* __restrict__ h2csr,              // E x 64 (CSR row order)
    float* __restrict__ ya_csr)             // E x 9  (CSR row order)
{
    __shared__ float S[12288 + 64];
    float* W1s = S;              // [128][64] 32 KB
    float* ES  = S + 8192;       // [64][64] 16 KB: es_t k-half (swizzled), h2 buf
    int*   pos_s = (int*)(S + 12288);

    const int t    = threadIdx.x;
    const int lane = t & 63;
    const int wid  = t >> 6;
    const int er   = lane & 3;   // edge sub-tile
    const int cc   = lane >> 2;  // channel sub-tile
    const int eb   = blockIdx.x * 64;

    // ---- stage W1 (8 f4/thr), linear, coalesced ----------------------------
    {
        const float4* s1 = (const float4*)rad_w1;
        float4* d1 = (float4*)W1s;
#pragma unroll
        for (int i = 0; i < 8; ++i) d1[t + i * 256] = s1[t + i * 256];
    }
    // ---- CSR positions + ya gather for this block's 64 edges ---------------
    if (t < 64) {
        int e = eb + t;
        int d = edge_dst[e];
        int p = offsets[d] + atomicAdd(&cursor[d], 1);
        pos_s[t] = p;
        const float* ya = edge_attr + (size_t)e * 9;
        float* dst = ya_csr + (size_t)p * 9;
#pragma unroll
        for (int k = 0; k < 9; ++k) dst[k] = ya[k];
    }
    // ---- stage es_t half0 (k=0..63), swizzled col = e ^ (seg<<3) -----------
    {
        const int re = t >> 2, seg = t & 3;
        const int col = re ^ (seg << 3);    // seg = k>>4
        const float* row = edge_scalars + (size_t)(eb + re) * 128;
#pragma unroll
        for (int q = 0; q < 4; ++q) {
            float4 v = *(const float4*)(row + seg * 16 + q * 4);
            ES[(seg * 16 + q * 4 + 0) * 64 + col] = v.x;
            ES[(seg * 16 + q * 4 + 1) * 64 + col] = v.y;
            ES[(seg * 16 + q * 4 + 2) * 64 + col] = v.z;
            ES[(seg * 16 + q * 4 + 3) * 64 + col] = v.w;
        }
    }
    __syncthreads();

    // per-lane channel params (n = cc*4+j)
    const int n0 = cc * 4;
    float b1v[4], g1v[4], t1v[4], b2v[4], g2v[4], t2v[4];
#pragma unroll
    for (int j = 0; j < 4; ++j) {
        b1v[j] = rad_b1[n0 + j]; g1v[j] = g1[n0 + j]; t1v[j] = bt1[n0 + j];
        b2v[j] = rad_b2[n0 + j]; g2v[j] = g2[n0 + j]; t2v[j] = bt2[n0 + j];
    }

    float acc[4][4];
#pragma unroll
    for (int i = 0; i < 4; ++i)
#pragma unroll
        for (int j = 0; j < 4; ++j) acc[i][j] = b1v[j];

    const int ecol = wid * 16 + er * 4;

    // ---- GEMM1 half0: k = 0..63 (read un-swizzles: col = ecol ^ ((k>>4)<<3))
#pragma unroll 8
    for (int k = 0; k < 64; ++k) {
        float4 av = *(const float4*)&ES[k * 64 + (ecol ^ (((k >> 4) & 3) << 3))];
        float4 wv = *(const float4*)&W1s[k * 64 + n0];    // 2-way (free)
        float a4[4] = {av.x, av.y, av.z, av.w};
        float w4[4] = {wv.x, wv.y, wv.z, wv.w};
#pragma unroll
        for (int i = 0; i < 4; ++i)
#pragma unroll
            for (int j = 0; j < 4; ++j) acc[i][j] = fmaf(a4[i], w4[j], acc[i][j]);
    }
    __syncthreads();
    // ---- stage es_t half1 (k=64..127), same swizzle ------------------------
    {
        const int re = t >> 2, seg = t & 3;
        const int col = re ^ (seg << 3);
        const float* row = edge_scalars + (size_t)(eb + re) * 128 + 64;
#pragma unroll
        for (int q = 0; q < 4; ++q) {
            float4 v = *(const float4*)(row + seg * 16 + q * 4);
            ES[(seg * 16 + q * 4 + 0) * 64 + col] = v.x;
            ES[(seg * 16 + q * 4 + 1) * 64 + col] = v.y;
            ES[(seg * 16 + q * 4 + 2) * 64 + col] = v.z;
            ES[(seg * 16 + q * 4 + 3) * 64 + col] = v.w;
        }
    }
    __syncthreads();
    // ---- GEMM1 half1: k = 64..127 ------------------------------------------
#pragma unroll 8
    for (int k = 0; k < 64; ++k) {
        float4 av = *(const float4*)&ES[k * 64 + (ecol ^ (((k >> 4) & 3) << 3))];
        float4 wv = *(const float4*)&W1s[(64 + k) * 64 + n0];
        float a4[4] = {av.x, av.y, av.z, av.w};
        float w4[4] = {wv.x, wv.y, wv.z, wv.w};
#pragma unroll
        for (int i = 0; i < 4; ++i)
#pragma unroll
            for (int j = 0; j < 4; ++j) acc[i][j] = fmaf(a4[i], w4[j], acc[i][j]);
    }
    __syncthreads();  // all ES reads complete; ES reusable for h2 assembly

    // ---- LN1 + silu IN PLACE: acc[i][j] becomes h1[e=wid*16+er*4+i][u=cc*4+j]
    {
        float s1i[4], s2i[4];
#pragma unroll
        for (int i = 0; i < 4; ++i) {
            s1i[i] = acc[i][0] + acc[i][1] + acc[i][2] + acc[i][3];
            s2i[i] = acc[i][0] * acc[i][0] + acc[i][1] * acc[i][1]
                   + acc[i][2] * acc[i][2] + acc[i][3] * acc[i][3];
        }
#pragma unroll
        for (int m = 4; m <= 32; m <<= 1) {
#pragma unroll
            for (int i = 0; i < 4; ++i) {
                s1i[i] += __shfl_xor(s1i[i], m, 64);
                s2i[i] += __shfl_xor(s2i[i], m, 64);
            }
        }
#pragma unroll
        for (int i = 0; i < 4; ++i) {
            float mu  = s1i[i] * (1.0f / 64.0f);
            float var = s2i[i] * (1.0f / 64.0f) - mu * mu;
            float rs  = rsqrtf(var + 1e-5f);
#pragma unroll
            for (int j = 0; j < 4; ++j) {
                float y = (acc[i][j] - mu) * rs * g1v[j] + t1v[j];
                acc[i][j] = silu_f(y);
            }
        }
    }

    // ---- GEMM2 via register shuffle: h1[e][u=4a+b] from lane a*4+er --------
    float acc2[4][4];
#pragma unroll
    for (int i = 0; i < 4; ++i)
#pragma unroll
        for (int j = 0; j < 4; ++j) acc2[i][j] = b2v[j];
#pragma unroll
    for (int a = 0; a < 16; ++a) {
        const int src = a * 4 + er;
#pragma unroll
        for (int b = 0; b < 4; ++b) {
            const int u = a * 4 + b;
            float hv[4];
#pragma unroll
            for (int i = 0; i < 4; ++i) hv[i] = __shfl(acc[i][b], src, 64);
            float4 wv = *(const float4*)&rad_w2[u * 64 + n0];  // VMEM (L1)
            float w4[4] = {wv.x, wv.y, wv.z, wv.w};
#pragma unroll
            for (int i = 0; i < 4; ++i)
#pragma unroll
                for (int j = 0; j < 4; ++j)
                    acc2[i][j] = fmaf(hv[i], w4[j], acc2[i][j]);
        }
    }

    // ---- LN2 + silu -> h2 rows assembled in (old ES) buffer ----------------
    {
        float s1i[4], s2i[4];
#pragma unroll
        for (int i = 0; i < 4; ++i) {
            s1i[i] = acc2[i][0] + acc2[i][1] + acc2[i][2] + acc2[i][3];
            s2i[i] = acc2[i][0] * acc2[i][0] + acc2[i][1] * acc2[i][1]
                   + acc2[i][2] * acc2[i][2] + acc2[i][3] * acc2[i][3];
        }
#pragma unroll
        for (int m = 4; m <= 32; m <<= 1) {
#pragma unroll
            for (int i = 0; i < 4; ++i) {
                s1i[i] += __shfl_xor(s1i[i], m, 64);
                s2i[i] += __shfl_xor(s2i[i], m, 64);
            }
        }
#pragma unroll
        for (int i = 0; i < 4; ++i) {
            float mu  = s1i[i] * (1.0f / 64.0f);
            float var = s2i[i] * (1.0f / 64.0f) - mu * mu;
            float rs  = rsqrtf(var + 1e-5f);
            float4 v;
            v.x = silu_f((acc2[i][0] - mu) * rs * g2v[0] + t2v[0]);
            v.y = silu_f((acc2[i][1] - mu) * rs * g2v[1] + t2v[1]);
            v.z = silu_f((acc2[i][2] - mu) * rs * g2v[2] + t2v[2]);
            v.w = silu_f((acc2[i][3] - mu) * rs * g2v[3] + t2v[3]);
            *(float4*)&ES[(wid * 16 + er * 4 + i) * 64 + n0] = v;
        }
    }
    __syncthreads();

    // ---- epilogue: coalesced float4 writes at CSR positions ----------------
    {
        const int r = t >> 2, p = t & 3;
        int pos = pos_s[r];
        float* dst = h2csr + (size_t)pos * 64 + p * 16;
        const float* src = &ES[r * 64 + p * 16];
#pragma unroll
        for (int q = 0; q < 4; ++q)
            *(float4*)(dst + q * 4) = *(const float4*)(src + q * 4);
    }
}

// ---- Phase B1: per-node T/ys build (wave per node, two linear streams) ------
__global__ __launch_bounds__(1024) void t_build(
    const float* __restrict__ h2csr,     // E x 64 (CSR order)
    const float* __restrict__ ya_csr,    // E x 9  (CSR order)
    const int*   __restrict__ offsets,   // NNODES+1
    float* __restrict__ Tbuf,            // NPAD x 9 x 64
    float* __restrict__ ysb)             // NPAD x 9
{
    const int lane = threadIdx.x & 63;
    const int n = __builtin_amdgcn_readfirstlane(blockIdx.x * 16 + (threadIdx.x >> 6));
    const int s0 = offsets[n], s1 = offsets[n + 1];

    float T[9]  = {0, 0, 0, 0, 0, 0, 0, 0, 0};
    float ys[9] = {0, 0, 0, 0, 0, 0, 0, 0, 0};
    for (int i = s0; i < s1; ++i) {
        float hv = h2csr[(size_t)i * 64 + lane];   // coalesced linear stream
        const float* ya = ya_csr + (size_t)i * 9;  // sequential uniform stream
#pragma unroll
        for (int k = 0; k < 9; ++k) {
            float y = ya[k];
            T[k] += hv * y;
            ys[k] += y;
        }
    }
    float* tb = Tbuf + (size_t)n * 576;
#pragma unroll
    for (int k = 0; k < 9; ++k) tb[k * 64 + lane] = T[k];
#pragma unroll
    for (int k = 0; k < 9; ++k) if (lane == k) ysb[n * 9 + k] = ys[k];
}

// ---- Phase B2: per-(node-tile, l) block GEMMs -------------------------------
__global__ __launch_bounds__(256) void proj(
    const float* __restrict__ Tbuf, const float* __restrict__ ysb,
    const int*   __restrict__ offsets,
    const float* __restrict__ M,      // 64 x 224
    const float* __restrict__ cvec,   // 224
    const float* __restrict__ proj_b, // 128
    float* __restrict__ out)          // NNODES x 480
{
    __shared__ float S[13248];
    const int tid = threadIdx.x;
    const int bid = blockIdx.x;
    constexpr float inv = 0.35355339059327373f;

    if (bid < NB_L0) {
        // l0: k=0, 64 nodes, cols 0..127
        const int n0 = bid * 64;
        for (int it = tid; it < 1024; it += 256) {      // T0 -> [u][66]
            int ni = it >> 4, q4 = it & 15;
            float4 v = *(const float4*)&Tbuf[(size_t)(n0 + ni) * 576 + q4 * 4];
            S[(q4 * 4 + 0) * 66 + ni] = v.x;
            S[(q4 * 4 + 1) * 66 + ni] = v.y;
            S[(q4 * 4 + 2) * 66 + ni] = v.z;
            S[(q4 * 4 + 3) * 66 + ni] = v.w;
        }
        for (int it = tid; it < 2048; it += 256) {      // M0 -> [u][128] @4224
            int u = it >> 5, c4 = it & 31;
            *(float4*)&S[4224 + u * 128 + c4 * 4] = *(const float4*)&M[u * 224 + c4 * 4];
        }
        __syncthreads();
        const int np = tid & 15, cg = tid >> 4;
        float acc[4][8];
#pragma unroll
        for (int i = 0; i < 4; ++i)
#pragma unroll
            for (int j = 0; j < 8; ++j) acc[i][j] = 0.0f;
#pragma unroll 4
        for (int u = 0; u < 64; ++u) {
            float4 tv = *(const float4*)&S[u * 66 + np * 4];
            float4 m0 = *(const float4*)&S[4224 + u * 128 + cg * 8];
            float4 m1 = *(const float4*)&S[4224 + u * 128 + cg * 8 + 4];
            float ta[4] = {tv.x, tv.y, tv.z, tv.w};
            float ma[8] = {m0.x, m0.y, m0.z, m0.w, m1.x, m1.y, m1.z, m1.w};
#pragma unroll
            for (int i = 0; i < 4; ++i)
#pragma unroll
                for (int j = 0; j < 8; ++j) acc[i][j] = fmaf(ta[i], ma[j], acc[i][j]);
        }
#pragma unroll
        for (int i = 0; i < 4; ++i) {
            int n = n0 + np * 4 + i;
            if (n >= NNODES) continue;
            float ys0 = ysb[n * 9];
            float cnt = (float)(offsets[n + 1] - offsets[n]);
            float f[8];
#pragma unroll
            for (int j = 0; j < 8; ++j) {
                int col = cg * 8 + j;
                f[j] = (acc[i][j] + cvec[col] * ys0 + cnt * proj_b[col]) * inv;
            }
            *(float4*)&out[(size_t)n * 480 + cg * 8]     = *(float4*)&f[0];
            *(float4*)&out[(size_t)n * 480 + cg * 8 + 4] = *(float4*)&f[4];
        }
    } else if (bid < NB_L0 + NB_L12) {
        // l1: k=1..3, 32 nodes, cols 128..319 (64 ch x 3)
        const int n0 = (bid - NB_L0) * 32;
        for (int it = tid; it < 1536; it += 256) {      // T1..3 -> [kq][u][34]
            int r = it >> 4, q4 = it & 15;
            int kq = r >> 5, ni = r & 31;
            float4 v = *(const float4*)&Tbuf[(size_t)(n0 + ni) * 576 + (1 + kq) * 64 + q4 * 4];
            float* dst = &S[kq * 2176];
            dst[(q4 * 4 + 0) * 34 + ni] = v.x;
            dst[(q4 * 4 + 1) * 34 + ni] = v.y;
            dst[(q4 * 4 + 2) * 34 + ni] = v.z;
            dst[(q4 * 4 + 3) * 34 + ni] = v.w;
        }
        for (int it = tid; it < 1024; it += 256) {      // M1 -> [u][64] @6528
            int u = it >> 4, c4 = it & 15;
            *(float4*)&S[6528 + u * 64 + c4 * 4] = *(const float4*)&M[u * 224 + 128 + c4 * 4];
        }
        __syncthreads();
        const int np = tid & 15, cg = tid >> 4;
        float acc[2][4][3];
#pragma unroll
        for (int i = 0; i < 2; ++i)
#pragma unroll
            for (int j = 0; j < 4; ++j)
#pragma unroll
                for (int kq = 0; kq < 3; ++kq) acc[i][j][kq] = 0.0f;
#pragma unroll 4
        for (int u = 0; u < 64; ++u) {
            float2 t0 = *(const float2*)&S[0 * 2176 + u * 34 + np * 2];
            float2 t1 = *(const float2*)&S[1 * 2176 + u * 34 + np * 2];
            float2 t2 = *(const float2*)&S[2 * 2176 + u * 34 + np * 2];
            float4 m  = *(const float4*)&S[6528 + u * 64 + cg * 4];
            float ma[4] = {m.x, m.y, m.z, m.w};
            float ta[2][3] = {{t0.x, t1.x, t2.x}, {t0.y, t1.y, t2.y}};
#pragma unroll
            for (int i = 0; i < 2; ++i)
#pragma unroll
                for (int j = 0; j < 4; ++j) {
                    acc[i][j][0] = fmaf(ta[i][0], ma[j], acc[i][j][0]);
                    acc[i][j][1] = fmaf(ta[i][1], ma[j], acc[i][j][1]);
                    acc[i][j][2] = fmaf(ta[i][2], ma[j], acc[i][j][2]);
                }
        }
#pragma unroll
        for (int i = 0; i < 2; ++i) {
            int n = n0 + np * 2 + i;
            if (n >= NNODES) continue;
            float y1 = ysb[n * 9 + 1], y2 = ysb[n * 9 + 2], y3 = ysb[n * 9 + 3];
            float f[12];
#pragma unroll
            for (int j = 0; j < 4; ++j) {
                int cc = cg * 4 + j;
                float cv = cvec[128 + cc];
                f[j * 3 + 0] = (acc[i][j][0] + cv * y1) * inv;
                f[j * 3 + 1] = (acc[i][j][1] + cv * y2) * inv;
                f[j * 3 + 2] = (acc[i][j][2] + cv * y3) * inv;
            }
            float* dst = &out[(size_t)n * 480 + 128 + cg * 12];
            *(float4*)(dst + 0) = *(float4*)&f[0];
            *(float4*)(dst + 4) = *(float4*)&f[4];
            *(float4*)(dst + 8) = *(float4*)&f[8];
        }
    } else {
        // l2: k=4..8, 32 nodes, cols 320..479 (32 ch x 5)
        const int n0 = (bid - NB_L0 - NB_L12) * 32;
        for (int it = tid; it < 2560; it += 256) {      // T4..8 -> [kq][u][34]
            int r = it >> 4, q4 = it & 15;
            int kq = r >> 5, ni = r & 31;
            float4 v = *(const float4*)&Tbuf[(size_t)(n0 + ni) * 576 + (4 + kq) * 64 + q4 * 4];
            float* dst = &S[kq * 2176];
            dst[(q4 * 4 + 0) * 34 + ni] = v.x;
            dst[(q4 * 4 + 1) * 34 + ni] = v.y;
            dst[(q4 * 4 + 2) * 34 + ni] = v.z;
            dst[(q4 * 4 + 3) * 34 + ni] = v.w;
        }
        for (int it = tid; it < 512; it += 256) {       // M2 -> [u][32] @10880
            int u = it >> 3, c4 = it & 7;
            *(float4*)&S[10880 + u * 32 + c4 * 4] = *(const float4*)&M[u * 224 + 192 + c4 * 4];
        }
        __syncthreads();
        const int np = tid & 15, cg = tid >> 4;
        float acc[2][2][5];
#pragma unroll
        for (int i = 0; i < 2; ++i)
#pragma unroll
            for (int j = 0; j < 2; ++j)
#pragma unroll
                for (int kq = 0; kq < 5; ++kq) acc[i][j][kq] = 0.0f;
#pragma unroll 4
        for (int u = 0; u < 64; ++u) {
            float2 tq[5];
#pragma unroll
            for (int kq = 0; kq < 5; ++kq)
                tq[kq] = *(const float2*)&S[kq * 2176 + u * 34 + np * 2];
            float2 m = *(const float2*)&S[10880 + u * 32 + cg * 2];
            float ma[2] = {m.x, m.y};
#pragma unroll
            for (int i = 0; i < 2; ++i) {
                float ti[5] = {(&tq[0].x)[i], (&tq[1].x)[i], (&tq[2].x)[i],
                               (&tq[3].x)[i], (&tq[4].x)[i]};
#pragma unroll
                for (int j = 0; j < 2; ++j)
#pragma unroll
                    for (int kq = 0; kq < 5; ++kq)
                        acc[i][j][kq] = fmaf(ti[kq], ma[j], acc[i][j][kq]);
            }
        }
#pragma unroll
        for (int i = 0; i < 2; ++i) {
            int n = n0 + np * 2 + i;
            if (n >= NNODES) continue;
            float yk[5];
#pragma unroll
            for (int kq = 0; kq < 5; ++kq) yk[kq] = ysb[n * 9 + 4 + kq];
            float f[10];
#pragma unroll
            for (int j = 0; j < 2; ++j) {
                int cc = cg * 2 + j;
                float cv = cvec[192 + cc];
#pragma unroll
                for (int kq = 0; kq < 5; ++kq)
                    f[j * 5 + kq] = (acc[i][j][kq] + cv * yk[kq]) * inv;
            }
            float* dst = &out[(size_t)n * 480 + 320 + cg * 10];
#pragma unroll
            for (int q = 0; q < 5; ++q)
                *(float2*)(dst + q * 2) = *(float2*)&f[q * 2];
        }
    }
}

extern "C" void kernel_launch(void* const* d_in, const int* in_sizes, int n_in,
                              void* d_out, int out_size, void* d_ws, size_t ws_size,
                              hipStream_t stream)
{
    const float* edge_attr    = (const float*)d_in[1];
    const float* edge_scalars = (const float*)d_in[2];
    const int*   edge_dst     = (const int*)d_in[4];
    const float* exp_w   = (const float*)d_in[6];
    const float* exp_b   = (const float*)d_in[7];
    const float* rad_w1  = (const float*)d_in[8];
    const float* rad_b1  = (const float*)d_in[9];
    const float* g1      = (const float*)d_in[10];
    const float* bt1     = (const float*)d_in[11];
    const float* rad_w2  = (const float*)d_in[12];
    const float* rad_b2  = (const float*)d_in[13];
    const float* g2      = (const float*)d_in[14];
    const float* bt2     = (const float*)d_in[15];
    const float* rad_w3  = (const float*)d_in[16];
    const float* rad_off = (const float*)d_in[17];
    const float* pw0     = (const float*)d_in[18];
    const float* pw1     = (const float*)d_in[19];
    const float* pw2     = (const float*)d_in[20];
    const float* proj_b  = (const float*)d_in[21];

    // Workspace (~47 MB)
    float* M       = (float*)d_ws;                        // 14336 f
    float* cvec    = M + 14336;                           // 224 f
    float* h2csr   = cvec + 224;                          // 5,120,000 f
    int*   counts  = (int*)(h2csr + (size_t)NEDGES * 64); // 10000
    int*   offsets = counts + NNODES;                     // 10001
    float* ya_csr  = (float*)(offsets + NNODES + 1);      // 720,000 f
    float* Tbuf    = ya_csr + (size_t)NEDGES * 9;         // NPAD*576 f
    float* ysb     = Tbuf + (size_t)NPAD * 576;           // NPAD*9 f

    hipMemsetAsync(counts, 0, NNODES * sizeof(int), stream);
    precompute_and_hist<<<165, 256, 0, stream>>>(exp_w, exp_b, rad_w3, rad_off,
        pw0, pw1, pw2, M, cvec, edge_dst, counts);
    scan_counts<<<1, 1024, 0, stream>>>(counts, offsets);
    edge_h2<<<NEDGES / 64, 256, 0, stream>>>(edge_scalars, edge_attr, edge_dst,
        offsets, counts, rad_w1, rad_b1, g1, bt1, rad_w2, rad_b2, g2, bt2,
        h2csr, ya_csr);
    t_build<<<NNODES / 16, 1024, 0, stream>>>(h2csr, ya_csr, offsets, Tbuf, ysb);
    proj<<<NB_L0 + 2 * NB_L12, 256, 0, stream>>>(Tbuf, ysb, offsets,
        M, cvec, proj_b, (float*)d_out);
}

// Round 20
// 109.081 us; speedup vs baseline: 1.2558x; 1.1257x over previous
//
#include <hip/hip_runtime.h>
#include <math.h>

// EdgeDegreeEmbeddingNetwork — algebraically reduced, scatter-free, CSR-ordered.
// fp32 everywhere. R20 = R17 verbatim (measured best: 109.2us).
//   R19 lesson: __shfl (dynamic lane) = ds_bpermute = DS PIPE, not VALU —
//   shfl-GEMM2 increased DS traffic. Reverted.
//   R18 lesson: fusing t_build into proj kills its latency-hiding parallelism.
//   Closed paths: 8x8 tiles (VGPR alloc cap), W1-from-global (L1 thrash),
//   MFMA (unexplained error floor), scatter/atomics (fabric traffic).
// Structure: memset -> [Mc + hist] -> scan -> edge_h2 (4x4-tile LDS GEMM,
// W1 in LDS + swizzled staging, W2 via L1, inline CSR+ya gather) ->
// t_build (10000 waves, two linear streams) -> proj (block GEMMs).

#define NEDGES 80000
#define NNODES 10000
#define NPAD   10048   // T buffer rows (157*64)
#define NB_L0  157     // ceil(10000/64)
#define NB_L12 313     // ceil(10000/32)

__device__ __forceinline__ float silu_f(float y) {
    return y / (1.0f + __expf(-y));
}

// ---- Fused: precompute M (64x224), c (224)  +  dst histogram ----------------
__global__ __launch_bounds__(256) void precompute_and_hist(
    const float* __restrict__ exp_w, const float* __restrict__ exp_b,
    const float* __restrict__ rad_w3,     // 64 x 960
    const float* __restrict__ rad_offset, // 960
    const float* __restrict__ proj_w0,    // 224 x 128 (rows 0..127 live)
    const float* __restrict__ proj_w1,    // 384 x 64
    const float* __restrict__ proj_w2,    // 352 x 32
    float* __restrict__ M, float* __restrict__ cvec,
    const int* __restrict__ edge_dst, int* __restrict__ counts)
{
    if (blockIdx.x >= 65) {
        int b = blockIdx.x - 65;
        for (int e = b * 256 + threadIdx.x; e < NEDGES; e += 100 * 256)
            atomicAdd(&counts[edge_dst[e]], 1);
        return;
    }
    __shared__ float x0[128];
    int t = threadIdx.x;
    if (t < 128) x0[t] = exp_w[t] + exp_b[t];
    __syncthreads();
    if (t >= 224) return;
    int h = blockIdx.x; // 0..63 -> M rows, 64 -> c
    const float* src = (h < 64) ? (rad_w3 + h * 960) : rad_offset;
    float acc = 0.0f;
    if (t < 128) {
#pragma unroll 4
        for (int u = 0; u < 128; ++u) acc += src[u] * x0[u] * proj_w0[u * 128 + t];
    } else if (t < 192) {
        int o = t - 128;
#pragma unroll 4
        for (int u = 0; u < 128; ++u) acc += src[128 + u] * x0[u] * proj_w1[u * 64 + o];
    } else {
        int o = t - 192;
#pragma unroll 4
        for (int u = 0; u < 128; ++u) acc += src[256 + u] * x0[u] * proj_w2[u * 32 + o];
    }
    if (h < 64) M[h * 224 + t] = acc;
    else        cvec[t] = acc;
}

// ---- CSR: exclusive scan of counts via wave shuffles -------------------------
__global__ __launch_bounds__(1024) void scan_counts(
    int* __restrict__ counts, int* __restrict__ offsets)
{
    __shared__ int wsum[16];
    const int t = threadIdx.x;
    const int lane = t & 63, w = t >> 6;
    const int base = t * 10;
    int local[10];
    int s = 0;
#pragma unroll
    for (int i = 0; i < 10; ++i) {
        int idx = base + i;
        int v = (idx < NNODES) ? counts[idx] : 0;
        local[i] = s;
        s += v;
    }
    int incl = s;
#pragma unroll
    for (int off = 1; off < 64; off <<= 1) {
        int up = __shfl_up(incl, off, 64);
        if (lane >= off) incl += up;
    }
    if (lane == 63) wsum[w] = incl;
    __syncthreads();
    if (t < 16) {
        int v = wsum[t];
#pragma unroll
        for (int off = 1; off < 16; off <<= 1) {
            int up = __shfl_up(v, off, 64);
            if (t >= off) v += up;
        }
        wsum[t] = v;
    }
    __syncthreads();
    int wbase = (w == 0) ? 0 : wsum[w - 1];
    int excl = wbase + incl - s;
#pragma unroll
    for (int i = 0; i < 10; ++i) {
        int idx = base + i;
        if (idx < NNODES) {
            offsets[idx] = excl + local[i];
            counts[idx] = 0;
        }
    }
    if (t == 1023) offsets[NNODES] = excl + s;
}

// ---- Phase A: 4x4 register-tiled LDS GEMM MLP (W1 in LDS, W2 via L1) --------
__global__ __launch_bounds__(256) void edge_h2(
    const float* __restrict__ edge_scalars, // E x 128
    const float* __restrict__ edge_attr,    // E x 9
    const int*   __restrict__ edge_dst,
    const int*   __restrict__ offsets,
    int*         __restrict__ cursor,
    const float* __restrict__ rad_w1,       // 128 x 64 [k][n]
    const float* __restrict__ rad_b1,
    const float* __restrict__ g1, const float* __restrict__ bt1,
    const float* __restrict__ rad_w2,       // 64 x 64 [u][n] (L1-hot, 16KB)
    const float* __restrict__ rad_b2,
    const float* __restrict__ g2, const float* __restrict__ bt2,
    float* __restrict__ h2csr,              // E x 64 (CSR row order)
    float* __restrict__ ya_csr)             // E x 9  (CSR row order)
{
    __shared__ float S[12288 + 64];
    float* W1s = S;              // [128][64] 32 KB; later: per-wave h1^T [64][20]
    float* ES  = S + 8192;       // [64][64] 16 KB: es_t k-half (swizzled), h2 buf
    int*   pos_s = (int*)(S + 12288);

    const int t    = threadIdx.x;
    const int lane = t & 63;
    const int wid  = t >> 6;
    const int er   = lane & 3;   // edge sub-tile
    const int cc   = lane >> 2;  // channel sub-tile
    const int eb   = blockIdx.x * 64;

    // ---- stage W1 (8 f4/thr), linear, coalesced ----------------------------
    {
        const float4* s1 = (const float4*)rad_w1;
        float4* d1 = (float4*)W1s;
#pragma unroll
        for (int i = 0; i < 8; ++i) d1[t + i * 256] = s1[t + i * 256];
    }
    // ---- CSR positions + ya gather for this block's 64 edges ---------------
    if (t < 64) {
        int e = eb + t;
        int d = edge_dst[e];
        int p = offsets[d] + atomicAdd(&cursor[d], 1);
        pos_s[t] = p;
        const float* ya = edge_attr + (size_t)e * 9;
        float* dst = ya_csr + (size_t)p * 9;
#pragma unroll
        for (int k = 0; k < 9; ++k) dst[k] = ya[k];
    }
    // ---- stage es_t half0 (k=0..63), swizzled col = e ^ (seg<<3) -----------
    {
        const int re = t >> 2, seg = t & 3;
        const int col = re ^ (seg << 3);    // seg = k>>4
        const float* row = edge_scalars + (size_t)(eb + re) * 128;
#pragma unroll
        for (int q = 0; q < 4; ++q) {
            float4 v = *(const float4*)(row + seg * 16 + q * 4);
            ES[(seg * 16 + q * 4 + 0) * 64 + col] = v.x;
            ES[(seg * 16 + q * 4 + 1) * 64 + col] = v.y;
            ES[(seg * 16 + q * 4 + 2) * 64 + col] = v.z;
            ES[(seg * 16 + q * 4 + 3) * 64 + col] = v.w;
        }
    }
    __syncthreads();

    // per-lane channel params (n = cc*4+j)
    const int n0 = cc * 4;
    float b1v[4], g1v[4], t1v[4], b2v[4], g2v[4], t2v[4];
#pragma unroll
    for (int j = 0; j < 4; ++j) {
        b1v[j] = rad_b1[n0 + j]; g1v[j] = g1[n0 + j]; t1v[j] = bt1[n0 + j];
        b2v[j] = rad_b2[n0 + j]; g2v[j] = g2[n0 + j]; t2v[j] = bt2[n0 + j];
    }

    float acc[4][4];
#pragma unroll
    for (int i = 0; i < 4; ++i)
#pragma unroll
        for (int j = 0; j < 4; ++j) acc[i][j] = b1v[j];

    const int ecol = wid * 16 + er * 4;

    // ---- GEMM1 half0: k = 0..63 (read un-swizzles: col = ecol ^ ((k>>4)<<3))
#pragma unroll 8
    for (int k = 0; k < 64; ++k) {
        float4 av = *(const float4*)&ES[k * 64 + (ecol ^ (((k >> 4) & 3) << 3))];
        float4 wv = *(const float4*)&W1s[k * 64 + n0];    // 2-way (free)
        float a4[4] = {av.x, av.y, av.z, av.w};
        float w4[4] = {wv.x, wv.y, wv.z, wv.w};
#pragma unroll
        for (int i = 0; i < 4; ++i)
#pragma unroll
            for (int j = 0; j < 4; ++j) acc[i][j] = fmaf(a4[i], w4[j], acc[i][j]);
    }
    __syncthreads();
    // ---- stage es_t half1 (k=64..127), same swizzle ------------------------
    {
        const int re = t >> 2, seg = t & 3;
        const int col = re ^ (seg << 3);
        const float* row = edge_scalars + (size_t)(eb + re) * 128 + 64;
#pragma unroll
        for (int q = 0; q < 4; ++q) {
            float4 v = *(const float4*)(row + seg * 16 + q * 4);
            ES[(seg * 16 + q * 4 + 0) * 64 + col] = v.x;
            ES[(seg * 16 + q * 4 + 1) * 64 + col] = v.y;
            ES[(seg * 16 + q * 4 + 2) * 64 + col] = v.z;
            ES[(seg * 16 + q * 4 + 3) * 64 + col] = v.w;
        }
    }
    __syncthreads();
    // ---- GEMM1 half1: k = 64..127 ------------------------------------------
#pragma unroll 8
    for (int k = 0; k < 64; ++k) {
        float4 av = *(const float4*)&ES[k * 64 + (ecol ^ (((k >> 4) & 3) << 3))];
        float4 wv = *(const float4*)&W1s[(64 + k) * 64 + n0];
        float a4[4] = {av.x, av.y, av.z, av.w};
        float w4[4] = {wv.x, wv.y, wv.z, wv.w};
#pragma unroll
        for (int i = 0; i < 4; ++i)
#pragma unroll
            for (int j = 0; j < 4; ++j) acc[i][j] = fmaf(a4[i], w4[j], acc[i][j]);
    }
    __syncthreads();  // all W1s/ES reads complete; regions reusable

    // ---- LN1 + silu -> h1^T tile in (old W1s) per-wave region [64][20] -----
    float* H = W1s + wid * 1280;
    {
        float s1i[4], s2i[4];
#pragma unroll
        for (int i = 0; i < 4; ++i) {
            s1i[i] = acc[i][0] + acc[i][1] + acc[i][2] + acc[i][3];
            s2i[i] = acc[i][0] * acc[i][0] + acc[i][1] * acc[i][1]
                   + acc[i][2] * acc[i][2] + acc[i][3] * acc[i][3];
        }
#pragma unroll
        for (int m = 4; m <= 32; m <<= 1) {
#pragma unroll
            for (int i = 0; i < 4; ++i) {
                s1i[i] += __shfl_xor(s1i[i], m, 64);
                s2i[i] += __shfl_xor(s2i[i], m, 64);
            }
        }
#pragma unroll
        for (int i = 0; i < 4; ++i) {
            float mu  = s1i[i] * (1.0f / 64.0f);
            float var = s2i[i] * (1.0f / 64.0f) - mu * mu;
            float rs  = rsqrtf(var + 1e-5f);
#pragma unroll
            for (int j = 0; j < 4; ++j) {
                float y = (acc[i][j] - mu) * rs * g1v[j] + t1v[j];
                H[(n0 + j) * 20 + er * 4 + i] = silu_f(y);
            }
        }
    }

    // ---- GEMM2: c = h1 @ W2 (h1 from LDS, W2 from global/L1) ---------------
    float acc2[4][4];
#pragma unroll
    for (int i = 0; i < 4; ++i)
#pragma unroll
        for (int j = 0; j < 4; ++j) acc2[i][j] = b2v[j];
#pragma unroll 8
    for (int u = 0; u < 64; ++u) {
        float4 hv = *(const float4*)&H[u * 20 + er * 4];   // DS, conflict-free
        float4 wv = *(const float4*)&rad_w2[u * 64 + n0];  // VMEM (L1, 16KB)
        float h4[4] = {hv.x, hv.y, hv.z, hv.w};
        float w4[4] = {wv.x, wv.y, wv.z, wv.w};
#pragma unroll
        for (int i = 0; i < 4; ++i)
#pragma unroll
            for (int j = 0; j < 4; ++j) acc2[i][j] = fmaf(h4[i], w4[j], acc2[i][j]);
    }

    // ---- LN2 + silu -> h2 rows assembled in (old ES) buffer ----------------
    {
        float s1i[4], s2i[4];
#pragma unroll
        for (int i = 0; i < 4; ++i) {
            s1i[i] = acc2[i][0] + acc2[i][1] + acc2[i][2] + acc2[i][3];
            s2i[i] = acc2[i][0] * acc2[i][0] + acc2[i][1] * acc2[i][1]
                   + acc2[i][2] * acc2[i][2] + acc2[i][3] * acc2[i][3];
        }
#pragma unroll
        for (int m = 4; m <= 32; m <<= 1) {
#pragma unroll
            for (int i = 0; i < 4; ++i) {
                s1i[i] += __shfl_xor(s1i[i], m, 64);
                s2i[i] += __shfl_xor(s2i[i], m, 64);
            }
        }
#pragma unroll
        for (int i = 0; i < 4; ++i) {
            float mu  = s1i[i] * (1.0f / 64.0f);
            float var = s2i[i] * (1.0f / 64.0f) - mu * mu;
            float rs  = rsqrtf(var + 1e-5f);
            float4 v;
            v.x = silu_f((acc2[i][0] - mu) * rs * g2v[0] + t2v[0]);
            v.y = silu_f((acc2[i][1] - mu) * rs * g2v[1] + t2v[1]);
            v.z = silu_f((acc2[i][2] - mu) * rs * g2v[2] + t2v[2]);
            v.w = silu_f((acc2[i][3] - mu) * rs * g2v[3] + t2v[3]);
            *(float4*)&ES[(wid * 16 + er * 4 + i) * 64 + n0] = v;
        }
    }
    __syncthreads();

    // ---- epilogue: coalesced float4 writes at CSR positions ----------------
    {
        const int r = t >> 2, p = t & 3;
        int pos = pos_s[r];
        float* dst = h2csr + (size_t)pos * 64 + p * 16;
        const float* src = &ES[r * 64 + p * 16];
#pragma unroll
        for (int q = 0; q < 4; ++q)
            *(float4*)(dst + q * 4) = *(const float4*)(src + q * 4);
    }
}

// ---- Phase B1: per-node T/ys build (wave per node, two linear streams) ------
__global__ __launch_bounds__(1024) void t_build(
    const float* __restrict__ h2csr,     // E x 64 (CSR order)
    const float* __restrict__ ya_csr,    // E x 9  (CSR order)
    const int*   __restrict__ offsets,   // NNODES+1
    float* __restrict__ Tbuf,            // NPAD x 9 x 64
    float* __restrict__ ysb)             // NPAD x 9
{
    const int lane = threadIdx.x & 63;
    const int n = __builtin_amdgcn_readfirstlane(blockIdx.x * 16 + (threadIdx.x >> 6));
    const int s0 = offsets[n], s1 = offsets[n + 1];

    float T[9]  = {0, 0, 0, 0, 0, 0, 0, 0, 0};
    float ys[9] = {0, 0, 0, 0, 0, 0, 0, 0, 0};
    for (int i = s0; i < s1; ++i) {
        float hv = h2csr[(size_t)i * 64 + lane];   // coalesced linear stream
        const float* ya = ya_csr + (size_t)i * 9;  // sequential uniform stream
#pragma unroll
        for (int k = 0; k < 9; ++k) {
            float y = ya[k];
            T[k] += hv * y;
            ys[k] += y;
        }
    }
    float* tb = Tbuf + (size_t)n * 576;
#pragma unroll
    for (int k = 0; k < 9; ++k) tb[k * 64 + lane] = T[k];
#pragma unroll
    for (int k = 0; k < 9; ++k) if (lane == k) ysb[n * 9 + k] = ys[k];
}

// ---- Phase B2: per-(node-tile, l) block GEMMs -------------------------------
__global__ __launch_bounds__(256) void proj(
    const float* __restrict__ Tbuf, const float* __restrict__ ysb,
    const int*   __restrict__ offsets,
    const float* __restrict__ M,      // 64 x 224
    const float* __restrict__ cvec,   // 224
    const float* __restrict__ proj_b, // 128
    float* __restrict__ out)          // NNODES x 480
{
    __shared__ float S[13248];
    const int tid = threadIdx.x;
    const int bid = blockIdx.x;
    constexpr float inv = 0.35355339059327373f;

    if (bid < NB_L0) {
        // l0: k=0, 64 nodes, cols 0..127
        const int n0 = bid * 64;
        for (int it = tid; it < 1024; it += 256) {      // T0 -> [u][66]
            int ni = it >> 4, q4 = it & 15;
            float4 v = *(const float4*)&Tbuf[(size_t)(n0 + ni) * 576 + q4 * 4];
            S[(q4 * 4 + 0) * 66 + ni] = v.x;
            S[(q4 * 4 + 1) * 66 + ni] = v.y;
            S[(q4 * 4 + 2) * 66 + ni] = v.z;
            S[(q4 * 4 + 3) * 66 + ni] = v.w;
        }
        for (int it = tid; it < 2048; it += 256) {      // M0 -> [u][128] @4224
            int u = it >> 5, c4 = it & 31;
            *(float4*)&S[4224 + u * 128 + c4 * 4] = *(const float4*)&M[u * 224 + c4 * 4];
        }
        __syncthreads();
        const int np = tid & 15, cg = tid >> 4;
        float acc[4][8];
#pragma unroll
        for (int i = 0; i < 4; ++i)
#pragma unroll
            for (int j = 0; j < 8; ++j) acc[i][j] = 0.0f;
#pragma unroll 4
        for (int u = 0; u < 64; ++u) {
            float4 tv = *(const float4*)&S[u * 66 + np * 4];
            float4 m0 = *(const float4*)&S[4224 + u * 128 + cg * 8];
            float4 m1 = *(const float4*)&S[4224 + u * 128 + cg * 8 + 4];
            float ta[4] = {tv.x, tv.y, tv.z, tv.w};
            float ma[8] = {m0.x, m0.y, m0.z, m0.w, m1.x, m1.y, m1.z, m1.w};
#pragma unroll
            for (int i = 0; i < 4; ++i)
#pragma unroll
                for (int j = 0; j < 8; ++j) acc[i][j] = fmaf(ta[i], ma[j], acc[i][j]);
        }
#pragma unroll
        for (int i = 0; i < 4; ++i) {
            int n = n0 + np * 4 + i;
            if (n >= NNODES) continue;
            float ys0 = ysb[n * 9];
            float cnt = (float)(offsets[n + 1] - offsets[n]);
            float f[8];
#pragma unroll
            for (int j = 0; j < 8; ++j) {
                int col = cg * 8 + j;
                f[j] = (acc[i][j] + cvec[col] * ys0 + cnt * proj_b[col]) * inv;
            }
            *(float4*)&out[(size_t)n * 480 + cg * 8]     = *(float4*)&f[0];
            *(float4*)&out[(size_t)n * 480 + cg * 8 + 4] = *(float4*)&f[4];
        }
    } else if (bid < NB_L0 + NB_L12) {
        // l1: k=1..3, 32 nodes, cols 128..319 (64 ch x 3)
        const int n0 = (bid - NB_L0) * 32;
        for (int it = tid; it < 1536; it += 256) {      // T1..3 -> [kq][u][34]
            int r = it >> 4, q4 = it & 15;
            int kq = r >> 5, ni = r & 31;
            float4 v = *(const float4*)&Tbuf[(size_t)(n0 + ni) * 576 + (1 + kq) * 64 + q4 * 4];
            float* dst = &S[kq * 2176];
            dst[(q4 * 4 + 0) * 34 + ni] = v.x;
            dst[(q4 * 4 + 1) * 34 + ni] = v.y;
            dst[(q4 * 4 + 2) * 34 + ni] = v.z;
            dst[(q4 * 4 + 3) * 34 + ni] = v.w;
        }
        for (int it = tid; it < 1024; it += 256) {      // M1 -> [u][64] @6528
            int u = it >> 4, c4 = it & 15;
            *(float4*)&S[6528 + u * 64 + c4 * 4] = *(const float4*)&M[u * 224 + 128 + c4 * 4];
        }
        __syncthreads();
        const int np = tid & 15, cg = tid >> 4;
        float acc[2][4][3];
#pragma unroll
        for (int i = 0; i < 2; ++i)
#pragma unroll
            for (int j = 0; j < 4; ++j)
#pragma unroll
                for (int kq = 0; kq < 3; ++kq) acc[i][j][kq] = 0.0f;
#pragma unroll 4
        for (int u = 0; u < 64; ++u) {
            float2 t0 = *(const float2*)&S[0 * 2176 + u * 34 + np * 2];
            float2 t1 = *(const float2*)&S[1 * 2176 + u * 34 + np * 2];
            float2 t2 = *(const float2*)&S[2 * 2176 + u * 34 + np * 2];
            float4 m  = *(const float4*)&S[6528 + u * 64 + cg * 4];
            float ma[4] = {m.x, m.y, m.z, m.w};
            float ta[2][3] = {{t0.x, t1.x, t2.x}, {t0.y, t1.y, t2.y}};
#pragma unroll
            for (int i = 0; i < 2; ++i)
#pragma unroll
                for (int j = 0; j < 4; ++j) {
                    acc[i][j][0] = fmaf(ta[i][0], ma[j], acc[i][j][0]);
                    acc[i][j][1] = fmaf(ta[i][1], ma[j], acc[i][j][1]);
                    acc[i][j][2] = fmaf(ta[i][2], ma[j], acc[i][j][2]);
                }
        }
#pragma unroll
        for (int i = 0; i < 2; ++i) {
            int n = n0 + np * 2 + i;
            if (n >= NNODES) continue;
            float y1 = ysb[n * 9 + 1], y2 = ysb[n * 9 + 2], y3 = ysb[n * 9 + 3];
            float f[12];
#pragma unroll
            for (int j = 0; j < 4; ++j) {
                int cc = cg * 4 + j;
                float cv = cvec[128 + cc];
                f[j * 3 + 0] = (acc[i][j][0] + cv * y1) * inv;
                f[j * 3 + 1] = (acc[i][j][1] + cv * y2) * inv;
                f[j * 3 + 2] = (acc[i][j][2] + cv * y3) * inv;
            }
            float* dst = &out[(size_t)n * 480 + 128 + cg * 12];
            *(float4*)(dst + 0) = *(float4*)&f[0];
            *(float4*)(dst + 4) = *(float4*)&f[4];
            *(float4*)(dst + 8) = *(float4*)&f[8];
        }
    } else {
        // l2: k=4..8, 32 nodes, cols 320..479 (32 ch x 5)
        const int n0 = (bid - NB_L0 - NB_L12) * 32;
        for (int it = tid; it < 2560; it += 256) {      // T4..8 -> [kq][u][34]
            int r = it >> 4, q4 = it & 15;
            int kq = r >> 5, ni = r & 31;
            float4 v = *(const float4*)&Tbuf[(size_t)(n0 + ni) * 576 + (4 + kq) * 64 + q4 * 4];
            float* dst = &S[kq * 2176];
            dst[(q4 * 4 + 0) * 34 + ni] = v.x;
            dst[(q4 * 4 + 1) * 34 + ni] = v.y;
            dst[(q4 * 4 + 2) * 34 + ni] = v.z;
            dst[(q4 * 4 + 3) * 34 + ni] = v.w;
        }
        for (int it = tid; it < 512; it += 256) {       // M2 -> [u][32] @10880
            int u = it >> 3, c4 = it & 7;
            *(float4*)&S[10880 + u * 32 + c4 * 4] = *(const float4*)&M[u * 224 + 192 + c4 * 4];
        }
        __syncthreads();
        const int np = tid & 15, cg = tid >> 4;
        float acc[2][2][5];
#pragma unroll
        for (int i = 0; i < 2; ++i)
#pragma unroll
            for (int j = 0; j < 2; ++j)
#pragma unroll
                for (int kq = 0; kq < 5; ++kq) acc[i][j][kq] = 0.0f;
#pragma unroll 4
        for (int u = 0; u < 64; ++u) {
            float2 tq[5];
#pragma unroll
            for (int kq = 0; kq < 5; ++kq)
                tq[kq] = *(const float2*)&S[kq * 2176 + u * 34 + np * 2];
            float2 m = *(const float2*)&S[10880 + u * 32 + cg * 2];
            float ma[2] = {m.x, m.y};
#pragma unroll
            for (int i = 0; i < 2; ++i) {
                float ti[5] = {(&tq[0].x)[i], (&tq[1].x)[i], (&tq[2].x)[i],
                               (&tq[3].x)[i], (&tq[4].x)[i]};
#pragma unroll
                for (int j = 0; j < 2; ++j)
#pragma unroll
                    for (int kq = 0; kq < 5; ++kq)
                        acc[i][j][kq] = fmaf(ti[kq], ma[j], acc[i][j][kq]);
            }
        }
#pragma unroll
        for (int i = 0; i < 2; ++i) {
            int n = n0 + np * 2 + i;
            if (n >= NNODES) continue;
            float yk[5];
#pragma unroll
            for (int kq = 0; kq < 5; ++kq) yk[kq] = ysb[n * 9 + 4 + kq];
            float f[10];
#pragma unroll
            for (int j = 0; j < 2; ++j) {
                int cc = cg * 2 + j;
                float cv = cvec[192 + cc];
#pragma unroll
                for (int kq = 0; kq < 5; ++kq)
                    f[j * 5 + kq] = (acc[i][j][kq] + cv * yk[kq]) * inv;
            }
            float* dst = &out[(size_t)n * 480 + 320 + cg * 10];
#pragma unroll
            for (int q = 0; q < 5; ++q)
                *(float2*)(dst + q * 2) = *(float2*)&f[q * 2];
        }
    }
}

extern "C" void kernel_launch(void* const* d_in, const int* in_sizes, int n_in,
                              void* d_out, int out_size, void* d_ws, size_t ws_size,
                              hipStream_t stream)
{
    const float* edge_attr    = (const float*)d_in[1];
    const float* edge_scalars = (const float*)d_in[2];
    const int*   edge_dst     = (const int*)d_in[4];
    const float* exp_w   = (const float*)d_in[6];
    const float* exp_b   = (const float*)d_in[7];
    const float* rad_w1  = (const float*)d_in[8];
    const float* rad_b1  = (const float*)d_in[9];
    const float* g1      = (const float*)d_in[10];
    const float* bt1     = (const float*)d_in[11];
    const float* rad_w2  = (const float*)d_in[12];
    const float* rad_b2  = (const float*)d_in[13];
    const float* g2      = (const float*)d_in[14];
    const float* bt2     = (const float*)d_in[15];
    const float* rad_w3  = (const float*)d_in[16];
    const float* rad_off = (const float*)d_in[17];
    const float* pw0     = (const float*)d_in[18];
    const float* pw1     = (const float*)d_in[19];
    const float* pw2     = (const float*)d_in[20];
    const float* proj_b  = (const float*)d_in[21];

    // Workspace (~47 MB)
    float* M       = (float*)d_ws;                        // 14336 f
    float* cvec    = M + 14336;                           // 224 f
    float* h2csr   = cvec + 224;                          // 5,120,000 f
    int*   counts  = (int*)(h2csr + (size_t)NEDGES * 64); // 10000
    int*   offsets = counts + NNODES;                     // 10001
    float* ya_csr  = (float*)(offsets + NNODES + 1);      // 720,000 f
    float* Tbuf    = ya_csr + (size_t)NEDGES * 9;         // NPAD*576 f
    float* ysb     = Tbuf + (size_t)NPAD * 576;           // NPAD*9 f

    hipMemsetAsync(counts, 0, NNODES * sizeof(int), stream);
    precompute_and_hist<<<165, 256, 0, stream>>>(exp_w, exp_b, rad_w3, rad_off,
        pw0, pw1, pw2, M, cvec, edge_dst, counts);
    scan_counts<<<1, 1024, 0, stream>>>(counts, offsets);
    edge_h2<<<NEDGES / 64, 256, 0, stream>>>(edge_scalars, edge_attr, edge_dst,
        offsets, counts, rad_w1, rad_b1, g1, bt1, rad_w2, rad_b2, g2, bt2,
        h2csr, ya_csr);
    t_build<<<NNODES / 16, 1024, 0, stream>>>(h2csr, ya_csr, offsets, Tbuf, ysb);
    proj<<<NB_L0 + 2 * NB_L12, 256, 0, stream>>>(Tbuf, ysb, offsets,
        M, cvec, proj_b, (float*)d_out);
}